// Round 1
// baseline (603.591 us; speedup 1.0000x reference)
//
#include <hip/hip_runtime.h>

// GCN 2-layer + linear head, N=100000 nodes, E=1600000 edges, f32.
// Reformulation: A@(x@W) == (A@x)@W  -> aggregate BEFORE the feature-expanding
// GEMM (64-dim scatter in layer 1) and AFTER the feature-shrinking GEMM
// (16-dim scatter in layer 2).

#define F_IN 64
#define H1DIM 128
#define H2DIM 16
#define C_OUT 10

__global__ void deg_kernel(const int* __restrict__ ei, int E, int N,
                           int* __restrict__ deg) {
    int stride = gridDim.x * blockDim.x;
    for (int i = blockIdx.x * blockDim.x + threadIdx.x; i < E; i += stride) {
        int d = ei[E + i];
        if ((unsigned)d < (unsigned)N) atomicAdd(&deg[d], 1);
    }
}

__global__ void dinv_kernel(const int* __restrict__ deg, int N,
                            float* __restrict__ dinv) {
    int i = blockIdx.x * blockDim.x + threadIdx.x;
    if (i < N) dinv[i] = rsqrtf((float)(deg[i] + 1));  // +1 self-loop
}

// agg1[i][f] = x[i][f] * dinv[i]^2   (self-loop term initializes the buffer)
__global__ void agg1_init(const float* __restrict__ x,
                          const float* __restrict__ dinv, int N,
                          float* __restrict__ agg1) {
    int stride = gridDim.x * blockDim.x;
    int total = N * F_IN;
    for (int t = blockIdx.x * blockDim.x + threadIdx.x; t < total; t += stride) {
        int i = t >> 6;
        float di = dinv[i];
        agg1[t] = x[t] * di * di;
    }
}

// One 64-lane wave per edge; lane = feature. agg1[dst] += x[src] * norm
__global__ void agg1_edge(const float* __restrict__ x,
                          const float* __restrict__ dinv,
                          const int* __restrict__ ei, int E, int N,
                          float* __restrict__ agg1) {
    int lane = threadIdx.x & 63;
    long long wave = (long long)(blockIdx.x * blockDim.x + threadIdx.x) >> 6;
    long long nw = ((long long)gridDim.x * blockDim.x) >> 6;
    for (long long e = wave; e < E; e += nw) {
        int s = ei[e], d = ei[E + e];
        if ((unsigned)s >= (unsigned)N || (unsigned)d >= (unsigned)N) continue;
        float norm = dinv[s] * dinv[d];
        atomicAdd(&agg1[(long long)d * F_IN + lane],
                  x[(long long)s * F_IN + lane] * norm);
    }
}

// z2 = relu(agg1 @ W1 + b1) @ W2    (h1 never materialized)
__global__ __launch_bounds__(256) void dense1_fused(
        const float* __restrict__ agg1, const float* __restrict__ W1,
        const float* __restrict__ b1, const float* __restrict__ W2, int N,
        float* __restrict__ z2) {
    __shared__ float sW1[F_IN * H1DIM];   // 32 KB
    __shared__ float sW2[H1DIM * H2DIM];  // 8 KB
    __shared__ float sb1[H1DIM];
    for (int t = threadIdx.x; t < F_IN * H1DIM; t += blockDim.x) sW1[t] = W1[t];
    for (int t = threadIdx.x; t < H1DIM * H2DIM; t += blockDim.x) sW2[t] = W2[t];
    for (int t = threadIdx.x; t < H1DIM; t += blockDim.x) sb1[t] = b1[t];
    __syncthreads();

    int i = blockIdx.x * blockDim.x + threadIdx.x;
    if (i >= N) return;

    float a[F_IN];
#pragma unroll
    for (int f = 0; f < F_IN; f++) a[f] = agg1[(long long)i * F_IN + f];

    float acc[H2DIM];
#pragma unroll
    for (int c = 0; c < H2DIM; c++) acc[c] = 0.f;

    for (int k = 0; k < H1DIM; k++) {
        float h = sb1[k];
#pragma unroll
        for (int f = 0; f < F_IN; f++) h = fmaf(a[f], sW1[f * H1DIM + k], h);
        h = fmaxf(h, 0.f);
#pragma unroll
        for (int c = 0; c < H2DIM; c++) acc[c] = fmaf(h, sW2[k * H2DIM + c], acc[c]);
    }
#pragma unroll
    for (int c = 0; c < H2DIM; c++) z2[(long long)i * H2DIM + c] = acc[c];
}

// agg2[i][c] = z2[i][c] * dinv[i]^2   (self-loop init)
__global__ void agg2_init(const float* __restrict__ z2,
                          const float* __restrict__ dinv, int N,
                          float* __restrict__ agg2) {
    int stride = gridDim.x * blockDim.x;
    int total = N * H2DIM;
    for (int t = blockIdx.x * blockDim.x + threadIdx.x; t < total; t += stride) {
        int i = t >> 4;
        float di = dinv[i];
        agg2[t] = z2[t] * di * di;
    }
}

// 16 lanes per edge (4 edges per wave). agg2[dst] += z2[src] * norm
__global__ void agg2_edge(const float* __restrict__ z2,
                          const float* __restrict__ dinv,
                          const int* __restrict__ ei, int E, int N,
                          float* __restrict__ agg2) {
    int tid = blockIdx.x * blockDim.x + threadIdx.x;
    int c = tid & 15;
    long long grp = (long long)tid >> 4;
    long long ngrp = ((long long)gridDim.x * blockDim.x) >> 4;
    for (long long e = grp; e < E; e += ngrp) {
        int s = ei[e], d = ei[E + e];
        if ((unsigned)s >= (unsigned)N || (unsigned)d >= (unsigned)N) continue;
        float norm = dinv[s] * dinv[d];
        atomicAdd(&agg2[(long long)d * H2DIM + c],
                  z2[(long long)s * H2DIM + c] * norm);
    }
}

// out = relu(agg2 + b2) @ Wl + bl
__global__ void final_kernel(const float* __restrict__ agg2,
                             const float* __restrict__ b2,
                             const float* __restrict__ Wl,
                             const float* __restrict__ bl, int N,
                             float* __restrict__ out) {
    __shared__ float sWl[H2DIM * C_OUT];
    __shared__ float sb2[H2DIM];
    __shared__ float sbl[C_OUT];
    for (int t = threadIdx.x; t < H2DIM * C_OUT; t += blockDim.x) sWl[t] = Wl[t];
    for (int t = threadIdx.x; t < H2DIM; t += blockDim.x) sb2[t] = b2[t];
    for (int t = threadIdx.x; t < C_OUT; t += blockDim.x) sbl[t] = bl[t];
    __syncthreads();

    int i = blockIdx.x * blockDim.x + threadIdx.x;
    if (i >= N) return;

    float h[H2DIM];
#pragma unroll
    for (int c = 0; c < H2DIM; c++)
        h[c] = fmaxf(agg2[(long long)i * H2DIM + c] + sb2[c], 0.f);

#pragma unroll
    for (int j = 0; j < C_OUT; j++) {
        float o = sbl[j];
#pragma unroll
        for (int c = 0; c < H2DIM; c++) o = fmaf(h[c], sWl[c * C_OUT + j], o);
        out[(long long)i * C_OUT + j] = o;
    }
}

extern "C" void kernel_launch(void* const* d_in, const int* in_sizes, int n_in,
                              void* d_out, int out_size, void* d_ws, size_t ws_size,
                              hipStream_t stream) {
    const float* x  = (const float*)d_in[0];
    const int*   ei = (const int*)d_in[1];   // [2, E] row-major: src row then dst row
    const float* W1 = (const float*)d_in[2];
    const float* b1 = (const float*)d_in[3];
    const float* W2 = (const float*)d_in[4];
    const float* b2 = (const float*)d_in[5];
    const float* Wl = (const float*)d_in[6];
    const float* bl = (const float*)d_in[7];
    float* out = (float*)d_out;

    const int N = in_sizes[0] / F_IN;
    const int E = in_sizes[1] / 2;

    // Workspace carve-up (256B aligned): deg, dinv, agg1, z2, agg2  (~39 MB)
    size_t off = 0;
    auto carve = [&](size_t bytes) {
        void* p = (char*)d_ws + off;
        off += (bytes + 255) & ~(size_t)255;
        return p;
    };
    int*   deg  = (int*)  carve((size_t)N * sizeof(int));
    float* dinv = (float*)carve((size_t)N * sizeof(float));
    float* agg1 = (float*)carve((size_t)N * F_IN * sizeof(float));
    float* z2   = (float*)carve((size_t)N * H2DIM * sizeof(float));
    float* agg2 = (float*)carve((size_t)N * H2DIM * sizeof(float));

    hipMemsetAsync(deg, 0, (size_t)N * sizeof(int), stream);

    deg_kernel<<<1024, 256, 0, stream>>>(ei, E, N, deg);
    dinv_kernel<<<(N + 255) / 256, 256, 0, stream>>>(deg, N, dinv);

    agg1_init<<<(N * F_IN + 255) / 256, 256, 0, stream>>>(x, dinv, N, agg1);
    agg1_edge<<<8192, 256, 0, stream>>>(x, dinv, ei, E, N, agg1);

    dense1_fused<<<(N + 255) / 256, 256, 0, stream>>>(agg1, W1, b1, W2, N, z2);

    agg2_init<<<(N * H2DIM + 255) / 256, 256, 0, stream>>>(z2, dinv, N, agg2);
    agg2_edge<<<8192, 256, 0, stream>>>(z2, dinv, ei, E, N, agg2);

    final_kernel<<<(N + 255) / 256, 256, 0, stream>>>(agg2, b2, Wl, bl, N, out);
}

// Round 2
// 451.918 us; speedup vs baseline: 1.3356x; 1.3356x over previous
//
#include <hip/hip_runtime.h>

// GCN 2-layer + head. Round 2: replace scatter-atomics with CSR gather.
// A@(x@W) == (A@x)@W  -> aggregate pre-GEMM (64 f) in L1, post-GEMM (16 f) in L2.
// agg[i] = (sum_{s->i} x[s]*dinv[s] + x[i]*dinv[i]) * dinv[i]   (self-loop folded)

#define F_IN 64
#define H1DIM 128
#define H2DIM 16
#define C_OUT 10
#define SCAN_BLK 256

__global__ void deg_kernel(const int* __restrict__ ei, int E, int N,
                           int* __restrict__ deg) {
    int e = blockIdx.x * blockDim.x + threadIdx.x;
    if (e < E) {
        int d = ei[E + e];
        if ((unsigned)d < (unsigned)N) atomicAdd(&deg[d], 1);
    }
}

__global__ void dinv_kernel(const int* __restrict__ deg, int N,
                            float* __restrict__ dinv) {
    int i = blockIdx.x * blockDim.x + threadIdx.x;
    if (i < N) dinv[i] = rsqrtf((float)(deg[i] + 1));  // +1 self-loop
}

// Inclusive Hillis-Steele per block; writes per-element EXCLUSIVE scan + block sum.
__global__ void scan_partial(const int* __restrict__ deg, int N,
                             int* __restrict__ row_off, int* __restrict__ bsum) {
    __shared__ int sh[SCAN_BLK];
    int tid = threadIdx.x;
    int gid = blockIdx.x * SCAN_BLK + tid;
    int v = (gid < N) ? deg[gid] : 0;
    sh[tid] = v;
    __syncthreads();
#pragma unroll
    for (int off = 1; off < SCAN_BLK; off <<= 1) {
        int t = (tid >= off) ? sh[tid - off] : 0;
        __syncthreads();
        sh[tid] += t;
        __syncthreads();
    }
    if (gid < N) row_off[gid] = sh[tid] - v;  // exclusive within block
    if (tid == SCAN_BLK - 1) bsum[blockIdx.x] = sh[tid];
}

// Single block scans the (<=512) block sums into exclusive form, in place.
__global__ void scan_bsums(int* __restrict__ bsum, int nb) {
    __shared__ int sh[512];
    int tid = threadIdx.x;
    int v = (tid < nb) ? bsum[tid] : 0;
    sh[tid] = v;
    __syncthreads();
#pragma unroll
    for (int off = 1; off < 512; off <<= 1) {
        int t = (tid >= off) ? sh[tid - off] : 0;
        __syncthreads();
        sh[tid] += t;
        __syncthreads();
    }
    if (tid < nb) bsum[tid] = sh[tid] - v;  // exclusive
}

__global__ void scan_finalize(const int* __restrict__ deg,
                              const int* __restrict__ bsum, int N,
                              int* __restrict__ row_off, int* __restrict__ cursor) {
    int gid = blockIdx.x * SCAN_BLK + threadIdx.x;
    if (gid < N) {
        int r = row_off[gid] + bsum[blockIdx.x];
        row_off[gid] = r;
        cursor[gid] = r;
        if (gid == N - 1) row_off[N] = r + deg[gid];
    }
}

__global__ void scatter_edges(const int* __restrict__ ei, int E, int N,
                              int* __restrict__ cursor, int* __restrict__ csr_src) {
    int e = blockIdx.x * blockDim.x + threadIdx.x;
    if (e < E) {
        int s = ei[e], d = ei[E + e];
        if ((unsigned)s < (unsigned)N && (unsigned)d < (unsigned)N) {
            int pos = atomicAdd(&cursor[d], 1);
            csr_src[pos] = s;
        }
    }
}

// One wave per node, lane = feature. No atomics.
__global__ __launch_bounds__(256) void gather1(
        const float* __restrict__ x, const float* __restrict__ dinv,
        const int* __restrict__ row_off, const int* __restrict__ csr_src,
        int N, float* __restrict__ agg1) {
    int node = blockIdx.x * 4 + (threadIdx.x >> 6);
    if (node >= N) return;
    int lane = threadIdx.x & 63;
    int beg = row_off[node], end = row_off[node + 1];
    float di = dinv[node];
    float acc = x[(long long)node * F_IN + lane] * di;  // self-loop
    int j = beg;
    for (; j + 4 <= end; j += 4) {
        int s0 = csr_src[j], s1 = csr_src[j + 1], s2 = csr_src[j + 2], s3 = csr_src[j + 3];
        float n0 = dinv[s0], n1 = dinv[s1], n2 = dinv[s2], n3 = dinv[s3];
        float v0 = x[(long long)s0 * F_IN + lane];
        float v1 = x[(long long)s1 * F_IN + lane];
        float v2 = x[(long long)s2 * F_IN + lane];
        float v3 = x[(long long)s3 * F_IN + lane];
        acc = fmaf(v0, n0, acc);
        acc = fmaf(v1, n1, acc);
        acc = fmaf(v2, n2, acc);
        acc = fmaf(v3, n3, acc);
    }
    for (; j < end; ++j) {
        int s = csr_src[j];
        acc = fmaf(x[(long long)s * F_IN + lane], dinv[s], acc);
    }
    agg1[(long long)node * F_IN + lane] = acc * di;
}

// z2 = relu(agg1 @ W1 + b1) @ W2
__global__ __launch_bounds__(256) void dense1_fused(
        const float* __restrict__ agg1, const float* __restrict__ W1,
        const float* __restrict__ b1, const float* __restrict__ W2, int N,
        float* __restrict__ z2) {
    __shared__ float sW1[F_IN * H1DIM];   // 32 KB
    __shared__ float sW2[H1DIM * H2DIM];  // 8 KB
    __shared__ float sb1[H1DIM];
    for (int t = threadIdx.x; t < F_IN * H1DIM; t += blockDim.x) sW1[t] = W1[t];
    for (int t = threadIdx.x; t < H1DIM * H2DIM; t += blockDim.x) sW2[t] = W2[t];
    for (int t = threadIdx.x; t < H1DIM; t += blockDim.x) sb1[t] = b1[t];
    __syncthreads();

    int i = blockIdx.x * blockDim.x + threadIdx.x;
    if (i >= N) return;

    float a[F_IN];
#pragma unroll
    for (int f = 0; f < F_IN; f++) a[f] = agg1[(long long)i * F_IN + f];

    float acc[H2DIM];
#pragma unroll
    for (int c = 0; c < H2DIM; c++) acc[c] = 0.f;

    for (int k = 0; k < H1DIM; k++) {
        float h = sb1[k];
#pragma unroll
        for (int f = 0; f < F_IN; f++) h = fmaf(a[f], sW1[f * H1DIM + k], h);
        h = fmaxf(h, 0.f);
#pragma unroll
        for (int c = 0; c < H2DIM; c++) acc[c] = fmaf(h, sW2[k * H2DIM + c], acc[c]);
    }
#pragma unroll
    for (int c = 0; c < H2DIM; c++) z2[(long long)i * H2DIM + c] = acc[c];
}

// One wave per node; 4 subgroups of 16 lanes stride the edge list; shuffle-reduce;
// fused relu + final linear head. No atomics, agg2 never materialized.
__global__ __launch_bounds__(256) void gather2_final(
        const float* __restrict__ z2, const float* __restrict__ dinv,
        const int* __restrict__ row_off, const int* __restrict__ csr_src,
        const float* __restrict__ b2, const float* __restrict__ Wl,
        const float* __restrict__ bl, int N, float* __restrict__ out) {
    int node = blockIdx.x * 4 + (threadIdx.x >> 6);
    if (node >= N) return;
    int lane = threadIdx.x & 63;
    int c = lane & 15, sub = lane >> 4;
    int beg = row_off[node], end = row_off[node + 1];
    float di = dinv[node];
    float acc = (sub == 0) ? z2[(long long)node * H2DIM + c] * di : 0.f;  // self-loop
    for (int j = beg + sub; j < end; j += 4) {
        int s = csr_src[j];
        acc = fmaf(z2[(long long)s * H2DIM + c], dinv[s], acc);
    }
    acc += __shfl_xor(acc, 16);
    acc += __shfl_xor(acc, 32);
    float h = fmaxf(acc * di + b2[c], 0.f);  // h for feature c (replicated x4)

    float o = (lane < C_OUT) ? bl[lane] : 0.f;
#pragma unroll
    for (int cc = 0; cc < 16; ++cc) {
        float hc = __shfl(h, cc);
        if (lane < C_OUT) o = fmaf(hc, Wl[cc * C_OUT + lane], o);
    }
    if (lane < C_OUT) out[(long long)node * C_OUT + lane] = o;
}

extern "C" void kernel_launch(void* const* d_in, const int* in_sizes, int n_in,
                              void* d_out, int out_size, void* d_ws, size_t ws_size,
                              hipStream_t stream) {
    const float* x  = (const float*)d_in[0];
    const int*   ei = (const int*)d_in[1];   // [2, E]: src row then dst row
    const float* W1 = (const float*)d_in[2];
    const float* b1 = (const float*)d_in[3];
    const float* W2 = (const float*)d_in[4];
    const float* b2 = (const float*)d_in[5];
    const float* Wl = (const float*)d_in[6];
    const float* bl = (const float*)d_in[7];
    float* out = (float*)d_out;

    const int N = in_sizes[0] / F_IN;
    const int E = in_sizes[1] / 2;

    size_t off = 0;
    auto carve = [&](size_t bytes) {
        void* p = (char*)d_ws + off;
        off += (bytes + 255) & ~(size_t)255;
        return p;
    };
    int*   deg     = (int*)  carve((size_t)N * sizeof(int));
    float* dinv    = (float*)carve((size_t)N * sizeof(float));
    int*   row_off = (int*)  carve(((size_t)N + 1) * sizeof(int));
    int*   cursor  = (int*)  carve((size_t)N * sizeof(int));
    int*   bsum    = (int*)  carve(512 * sizeof(int));
    int*   csr_src = (int*)  carve((size_t)E * sizeof(int));
    float* agg1    = (float*)carve((size_t)N * F_IN * sizeof(float));
    float* z2      = (float*)carve((size_t)N * H2DIM * sizeof(float));

    const int nb = (N + SCAN_BLK - 1) / SCAN_BLK;  // 391 <= 512

    hipMemsetAsync(deg, 0, (size_t)N * sizeof(int), stream);
    deg_kernel<<<(E + 255) / 256, 256, 0, stream>>>(ei, E, N, deg);
    dinv_kernel<<<(N + 255) / 256, 256, 0, stream>>>(deg, N, dinv);

    scan_partial<<<nb, SCAN_BLK, 0, stream>>>(deg, N, row_off, bsum);
    scan_bsums<<<1, 512, 0, stream>>>(bsum, nb);
    scan_finalize<<<nb, SCAN_BLK, 0, stream>>>(deg, bsum, N, row_off, cursor);

    scatter_edges<<<(E + 255) / 256, 256, 0, stream>>>(ei, E, N, cursor, csr_src);

    gather1<<<(N + 3) / 4, 256, 0, stream>>>(x, dinv, row_off, csr_src, N, agg1);
    dense1_fused<<<(N + 255) / 256, 256, 0, stream>>>(agg1, W1, b1, W2, N, z2);
    gather2_final<<<(N + 3) / 4, 256, 0, stream>>>(z2, dinv, row_off, csr_src,
                                                   b2, Wl, bl, N, out);
}

// Round 3
// 306.350 us; speedup vs baseline: 1.9703x; 1.4752x over previous
//
#include <hip/hip_runtime.h>

// GCN 2-layer + head. Round 3: CSR build via dst-bucketed radix partition
// (no random-position 4B scatters, no global deg atomics, no 3-kernel scan).
// Algebra: A@(x@W) == (A@x)@W -> aggregate pre-GEMM (64f) L1, post-GEMM (16f) L2.
// agg[i] = (sum_{s->i} x[s]*dinv[s] + x[i]*dinv[i]) * dinv[i]

#define F_IN 64
#define H1DIM 128
#define H2DIM 16
#define C_OUT 10

#define NB 1024        // bucket capacity (power of 2)
#define BSZ_LOG 7      // 128 nodes per bucket -> bucket = dst >> 7
#define SC_PER_TH 16   // edges per thread in bucket_scatter (4096/block)

__global__ void bucket_count(const int* __restrict__ ei, int E,
                             int* __restrict__ bucket_cnt) {
    __shared__ int h[NB];
    for (int t = threadIdx.x; t < NB; t += blockDim.x) h[t] = 0;
    __syncthreads();
    int stride = gridDim.x * blockDim.x;
    for (int e = blockIdx.x * blockDim.x + threadIdx.x; e < E; e += stride) {
        int d = ei[E + e];
        atomicAdd(&h[d >> BSZ_LOG], 1);
    }
    __syncthreads();
    for (int t = threadIdx.x; t < NB; t += blockDim.x)
        if (h[t]) atomicAdd(&bucket_cnt[t], h[t]);
}

__global__ void bucket_scan(const int* __restrict__ bucket_cnt,
                            int* __restrict__ bucket_off,
                            int* __restrict__ bucket_cursor) {
    __shared__ int sh[NB];
    int tid = threadIdx.x;
    int v = bucket_cnt[tid];
    sh[tid] = v;
    __syncthreads();
#pragma unroll
    for (int off = 1; off < NB; off <<= 1) {
        int t = (tid >= off) ? sh[tid - off] : 0;
        __syncthreads();
        sh[tid] += t;
        __syncthreads();
    }
    int ex = sh[tid] - v;
    bucket_off[tid] = ex;
    bucket_cursor[tid] = ex;
    if (tid == NB - 1) bucket_off[NB] = sh[tid];
}

// Each block: 4096-edge chunk. LDS hist -> one global atomic per (block,bucket)
// -> rank via LDS cursor -> write packed (d<<32|s) pairs bucket-major.
__global__ __launch_bounds__(256) void bucket_scatter(
        const int* __restrict__ ei, int E,
        int* __restrict__ bucket_cursor, unsigned long long* __restrict__ pairs) {
    __shared__ int cnt[NB];
    __shared__ int base[NB];
    for (int t = threadIdx.x; t < NB; t += 256) cnt[t] = 0;
    __syncthreads();

    long long chunk = (long long)blockIdx.x * (256 * SC_PER_TH);
    int s_[SC_PER_TH], d_[SC_PER_TH];
    int m = 0;
#pragma unroll
    for (int k = 0; k < SC_PER_TH; k++) {
        long long e = chunk + k * 256 + threadIdx.x;
        if (e < E) { s_[m] = ei[e]; d_[m] = ei[E + e]; m++; }
    }
    for (int k = 0; k < m; k++) atomicAdd(&cnt[d_[k] >> BSZ_LOG], 1);
    __syncthreads();
    for (int t = threadIdx.x; t < NB; t += 256) {
        int c = cnt[t];
        base[t] = c ? atomicAdd(&bucket_cursor[t], c) : 0;
        cnt[t] = 0;
    }
    __syncthreads();
    for (int k = 0; k < m; k++) {
        int b = d_[k] >> BSZ_LOG;
        int pos = base[b] + atomicAdd(&cnt[b], 1);
        pairs[pos] = ((unsigned long long)(unsigned)d_[k] << 32) | (unsigned)s_[k];
    }
}

// One block per bucket (128 nodes): LDS hist -> dinv + row_off (scan) ->
// csr_src scatter into the bucket's contiguous global window.
__global__ __launch_bounds__(256) void build_csr(
        const unsigned long long* __restrict__ pairs,
        const int* __restrict__ bucket_off, int N,
        float* __restrict__ dinv, int* __restrict__ row_off,
        int* __restrict__ csr_src) {
    int b = blockIdx.x;
    int base_node = b << BSZ_LOG;
    int nn = min(128, N - base_node);
    __shared__ int cnt[128];
    __shared__ int sc[128];
    __shared__ int cur[128];
    int tid = threadIdx.x;
    if (tid < 128) cnt[tid] = 0;
    __syncthreads();

    int pbeg = bucket_off[b], pend = bucket_off[b + 1];
    for (int j = pbeg + tid; j < pend; j += 256)
        atomicAdd(&cnt[(int)(pairs[j] >> 32) - base_node], 1);
    __syncthreads();

    int v = (tid < 128) ? cnt[tid] : 0;
    if (tid < 128) sc[tid] = v;
    __syncthreads();
#pragma unroll
    for (int off = 1; off < 128; off <<= 1) {
        int t = (tid < 128 && tid >= off) ? sc[tid - off] : 0;
        __syncthreads();
        if (tid < 128) sc[tid] += t;
        __syncthreads();
    }
    if (tid < nn) {
        int ro = pbeg + sc[tid] - v;
        row_off[base_node + tid] = ro;
        cur[tid] = ro;
        dinv[base_node + tid] = rsqrtf((float)(v + 1));  // +1 self-loop
    }
    if (b == 0 && tid == 0) row_off[N] = bucket_off[NB];
    __syncthreads();

    for (int j = pbeg + tid; j < pend; j += 256) {
        unsigned long long p = pairs[j];
        int d = (int)(p >> 32), s = (int)(p & 0xffffffffu);
        int pos = atomicAdd(&cur[d - base_node], 1);
        csr_src[pos] = s;
    }
}

// One wave per node, lane = feature. No atomics.
__global__ __launch_bounds__(256) void gather1(
        const float* __restrict__ x, const float* __restrict__ dinv,
        const int* __restrict__ row_off, const int* __restrict__ csr_src,
        int N, float* __restrict__ agg1) {
    int node = blockIdx.x * 4 + (threadIdx.x >> 6);
    if (node >= N) return;
    int lane = threadIdx.x & 63;
    int beg = row_off[node], end = row_off[node + 1];
    float di = dinv[node];
    float acc = x[(long long)node * F_IN + lane] * di;  // self-loop
    int j = beg;
    for (; j + 4 <= end; j += 4) {
        int s0 = csr_src[j], s1 = csr_src[j + 1], s2 = csr_src[j + 2], s3 = csr_src[j + 3];
        float n0 = dinv[s0], n1 = dinv[s1], n2 = dinv[s2], n3 = dinv[s3];
        float v0 = x[(long long)s0 * F_IN + lane];
        float v1 = x[(long long)s1 * F_IN + lane];
        float v2 = x[(long long)s2 * F_IN + lane];
        float v3 = x[(long long)s3 * F_IN + lane];
        acc = fmaf(v0, n0, acc);
        acc = fmaf(v1, n1, acc);
        acc = fmaf(v2, n2, acc);
        acc = fmaf(v3, n3, acc);
    }
    for (; j < end; ++j) {
        int s = csr_src[j];
        acc = fmaf(x[(long long)s * F_IN + lane], dinv[s], acc);
    }
    agg1[(long long)node * F_IN + lane] = acc * di;
}

// z2 = relu(agg1 @ W1 + b1) @ W2
__global__ __launch_bounds__(256) void dense1_fused(
        const float* __restrict__ agg1, const float* __restrict__ W1,
        const float* __restrict__ b1, const float* __restrict__ W2, int N,
        float* __restrict__ z2) {
    __shared__ float sW1[F_IN * H1DIM];
    __shared__ float sW2[H1DIM * H2DIM];
    __shared__ float sb1[H1DIM];
    for (int t = threadIdx.x; t < F_IN * H1DIM; t += blockDim.x) sW1[t] = W1[t];
    for (int t = threadIdx.x; t < H1DIM * H2DIM; t += blockDim.x) sW2[t] = W2[t];
    for (int t = threadIdx.x; t < H1DIM; t += blockDim.x) sb1[t] = b1[t];
    __syncthreads();

    int i = blockIdx.x * blockDim.x + threadIdx.x;
    if (i >= N) return;

    float a[F_IN];
#pragma unroll
    for (int f = 0; f < F_IN; f++) a[f] = agg1[(long long)i * F_IN + f];

    float acc[H2DIM];
#pragma unroll
    for (int c = 0; c < H2DIM; c++) acc[c] = 0.f;

    for (int k = 0; k < H1DIM; k++) {
        float h = sb1[k];
#pragma unroll
        for (int f = 0; f < F_IN; f++) h = fmaf(a[f], sW1[f * H1DIM + k], h);
        h = fmaxf(h, 0.f);
#pragma unroll
        for (int c = 0; c < H2DIM; c++) acc[c] = fmaf(h, sW2[k * H2DIM + c], acc[c]);
    }
#pragma unroll
    for (int c = 0; c < H2DIM; c++) z2[(long long)i * H2DIM + c] = acc[c];
}

// One wave per node; 4x16-lane subgroups stride edges; shuffle-reduce;
// fused relu + final head.
__global__ __launch_bounds__(256) void gather2_final(
        const float* __restrict__ z2, const float* __restrict__ dinv,
        const int* __restrict__ row_off, const int* __restrict__ csr_src,
        const float* __restrict__ b2, const float* __restrict__ Wl,
        const float* __restrict__ bl, int N, float* __restrict__ out) {
    int node = blockIdx.x * 4 + (threadIdx.x >> 6);
    if (node >= N) return;
    int lane = threadIdx.x & 63;
    int c = lane & 15, sub = lane >> 4;
    int beg = row_off[node], end = row_off[node + 1];
    float di = dinv[node];
    float acc = (sub == 0) ? z2[(long long)node * H2DIM + c] * di : 0.f;
    for (int j = beg + sub; j < end; j += 4) {
        int s = csr_src[j];
        acc = fmaf(z2[(long long)s * H2DIM + c], dinv[s], acc);
    }
    acc += __shfl_xor(acc, 16);
    acc += __shfl_xor(acc, 32);
    float h = fmaxf(acc * di + b2[c], 0.f);

    float o = (lane < C_OUT) ? bl[lane] : 0.f;
#pragma unroll
    for (int cc = 0; cc < 16; ++cc) {
        float hc = __shfl(h, cc);
        if (lane < C_OUT) o = fmaf(hc, Wl[cc * C_OUT + lane], o);
    }
    if (lane < C_OUT) out[(long long)node * C_OUT + lane] = o;
}

extern "C" void kernel_launch(void* const* d_in, const int* in_sizes, int n_in,
                              void* d_out, int out_size, void* d_ws, size_t ws_size,
                              hipStream_t stream) {
    const float* x  = (const float*)d_in[0];
    const int*   ei = (const int*)d_in[1];   // [2, E]: src row then dst row
    const float* W1 = (const float*)d_in[2];
    const float* b1 = (const float*)d_in[3];
    const float* W2 = (const float*)d_in[4];
    const float* b2 = (const float*)d_in[5];
    const float* Wl = (const float*)d_in[6];
    const float* bl = (const float*)d_in[7];
    float* out = (float*)d_out;

    const int N = in_sizes[0] / F_IN;
    const int E = in_sizes[1] / 2;

    size_t off = 0;
    auto carve = [&](size_t bytes) {
        void* p = (char*)d_ws + off;
        off += (bytes + 255) & ~(size_t)255;
        return p;
    };
    float* dinv    = (float*)carve((size_t)N * sizeof(float));
    int*   row_off = (int*)  carve(((size_t)N + 1) * sizeof(int));
    int*   csr_src = (int*)  carve((size_t)E * sizeof(int));
    float* agg1    = (float*)carve((size_t)N * F_IN * sizeof(float));
    float* z2      = (float*)carve((size_t)N * H2DIM * sizeof(float));
    int*   bcnt    = (int*)  carve(NB * sizeof(int));
    int*   boff    = (int*)  carve((NB + 1) * sizeof(int));
    int*   bcur    = (int*)  carve(NB * sizeof(int));
    // pairs aliases agg1 (E*8B = 12.8MB <= N*64*4B = 25.6MB); pairs are dead
    // before gather1 writes agg1 (stream-ordered).
    unsigned long long* pairs = (unsigned long long*)agg1;

    const int nbuckets_used = (N + (1 << BSZ_LOG) - 1) >> BSZ_LOG;  // 782

    hipMemsetAsync(bcnt, 0, NB * sizeof(int), stream);
    bucket_count<<<208, 256, 0, stream>>>(ei, E, bcnt);
    bucket_scan<<<1, NB, 0, stream>>>(bcnt, boff, bcur);
    bucket_scatter<<<(E + 256 * SC_PER_TH - 1) / (256 * SC_PER_TH), 256, 0, stream>>>(
        ei, E, bcur, pairs);
    build_csr<<<nbuckets_used, 256, 0, stream>>>(pairs, boff, N, dinv, row_off, csr_src);

    gather1<<<(N + 3) / 4, 256, 0, stream>>>(x, dinv, row_off, csr_src, N, agg1);
    dense1_fused<<<(N + 255) / 256, 256, 0, stream>>>(agg1, W1, b1, W2, N, z2);
    gather2_final<<<(N + 3) / 4, 256, 0, stream>>>(z2, dinv, row_off, csr_src,
                                                   b2, Wl, bl, N, out);
}

// Round 4
// 247.524 us; speedup vs baseline: 2.4385x; 1.2377x over previous
//
#include <hip/hip_runtime.h>
#include <hip/hip_fp16.h>

// GCN 2-layer + head. Round 4: fp16 gather tables (pre-scaled by dinv[src]),
// fused into the CSR build / dense kernels. Accumulation stays f32.
// Algebra: A@(x@W) == (A@x)@W -> aggregate pre-GEMM (64f) L1, post-GEMM (16f) L2.
// agg[i] = (sum_{s->i} xs[s] + xs[i]) * dinv[i],  xs[s] = x[s]*dinv[s] (fp16)

#define F_IN 64
#define H1DIM 128
#define H2DIM 16
#define C_OUT 10

#define NB 1024        // number of buckets (power of 2)
#define BSZ_LOG 7      // 128 nodes per bucket -> bucket = dst >> 7
#define SC_PER_TH 16   // edges per thread in bucket_scatter (4096/block)

__global__ void bucket_count(const int* __restrict__ ei, int E,
                             int* __restrict__ bucket_cnt) {
    __shared__ int h[NB];
    for (int t = threadIdx.x; t < NB; t += blockDim.x) h[t] = 0;
    __syncthreads();
    int stride = gridDim.x * blockDim.x;
    for (int e = blockIdx.x * blockDim.x + threadIdx.x; e < E; e += stride) {
        int d = ei[E + e];
        atomicAdd(&h[d >> BSZ_LOG], 1);
    }
    __syncthreads();
    for (int t = threadIdx.x; t < NB; t += blockDim.x)
        if (h[t]) atomicAdd(&bucket_cnt[t], h[t]);
}

__global__ void bucket_scan(const int* __restrict__ bucket_cnt,
                            int* __restrict__ bucket_off,
                            int* __restrict__ bucket_cursor) {
    __shared__ int sh[NB];
    int tid = threadIdx.x;
    int v = bucket_cnt[tid];
    sh[tid] = v;
    __syncthreads();
#pragma unroll
    for (int off = 1; off < NB; off <<= 1) {
        int t = (tid >= off) ? sh[tid - off] : 0;
        __syncthreads();
        sh[tid] += t;
        __syncthreads();
    }
    int ex = sh[tid] - v;
    bucket_off[tid] = ex;
    bucket_cursor[tid] = ex;
    if (tid == NB - 1) bucket_off[NB] = sh[tid];
}

// Each block: 4096-edge chunk. LDS hist -> one global atomic per (block,bucket)
// -> rank via LDS cursor -> write packed (d<<32|s) pairs bucket-major.
__global__ __launch_bounds__(256) void bucket_scatter(
        const int* __restrict__ ei, int E,
        int* __restrict__ bucket_cursor, unsigned long long* __restrict__ pairs) {
    __shared__ int cnt[NB];
    __shared__ int base[NB];
    for (int t = threadIdx.x; t < NB; t += 256) cnt[t] = 0;
    __syncthreads();

    long long chunk = (long long)blockIdx.x * (256 * SC_PER_TH);
    int s_[SC_PER_TH], d_[SC_PER_TH];
    int m = 0;
#pragma unroll
    for (int k = 0; k < SC_PER_TH; k++) {
        long long e = chunk + k * 256 + threadIdx.x;
        if (e < E) { s_[m] = ei[e]; d_[m] = ei[E + e]; m++; }
    }
    for (int k = 0; k < m; k++) atomicAdd(&cnt[d_[k] >> BSZ_LOG], 1);
    __syncthreads();
    for (int t = threadIdx.x; t < NB; t += 256) {
        int c = cnt[t];
        base[t] = c ? atomicAdd(&bucket_cursor[t], c) : 0;
        cnt[t] = 0;
    }
    __syncthreads();
    for (int k = 0; k < m; k++) {
        int b = d_[k] >> BSZ_LOG;
        int pos = base[b] + atomicAdd(&cnt[b], 1);
        pairs[pos] = ((unsigned long long)(unsigned)d_[k] << 32) | (unsigned)s_[k];
    }
}

// One block per bucket (128 nodes): LDS hist -> dinv + row_off (scan) ->
// csr_src scatter into contiguous window -> convert x rows to fp16*dinv.
__global__ __launch_bounds__(256) void build_csr_convert(
        const unsigned long long* __restrict__ pairs,
        const int* __restrict__ bucket_off,
        const float* __restrict__ x, int N,
        float* __restrict__ dinv, int* __restrict__ row_off,
        int* __restrict__ csr_src, __half2* __restrict__ xh2) {
    int b = blockIdx.x;
    int base_node = b << BSZ_LOG;
    int nn = min(128, N - base_node);
    __shared__ int cnt[128];
    __shared__ int sc[128];
    __shared__ int cur[128];
    __shared__ float sdi[128];
    int tid = threadIdx.x;
    if (tid < 128) cnt[tid] = 0;
    __syncthreads();

    int pbeg = bucket_off[b], pend = bucket_off[b + 1];
    for (int j = pbeg + tid; j < pend; j += 256)
        atomicAdd(&cnt[(int)(pairs[j] >> 32) - base_node], 1);
    __syncthreads();

    int v = (tid < 128) ? cnt[tid] : 0;
    if (tid < 128) sc[tid] = v;
    __syncthreads();
#pragma unroll
    for (int off = 1; off < 128; off <<= 1) {
        int t = (tid < 128 && tid >= off) ? sc[tid - off] : 0;
        __syncthreads();
        if (tid < 128) sc[tid] += t;
        __syncthreads();
    }
    if (tid < nn) {
        int ro = pbeg + sc[tid] - v;
        row_off[base_node + tid] = ro;
        cur[tid] = ro;
        float di = rsqrtf((float)(v + 1));  // +1 self-loop
        dinv[base_node + tid] = di;
        sdi[tid] = di;
    }
    if (b == 0 && tid == 0) row_off[N] = bucket_off[NB];
    __syncthreads();

    for (int j = pbeg + tid; j < pend; j += 256) {
        unsigned long long p = pairs[j];
        int d = (int)(p >> 32), s = (int)(p & 0xffffffffu);
        int pos = atomicAdd(&cur[d - base_node], 1);
        csr_src[pos] = s;
    }

    // xh2[i][l] = half2(x[i][2l], x[i][2l+1]) * dinv[i]
    const float2* x2 = (const float2*)x;
    int total = nn * 32;
    for (int t = tid; t < total; t += 256) {
        int nl = t >> 5, l = t & 31;
        float di = sdi[nl];
        long long idx = (long long)(base_node + nl) * 32 + l;
        float2 xv = x2[idx];
        xh2[idx] = __floats2half2_rn(xv.x * di, xv.y * di);
    }
}

// 32-lane group per node, lane = half2 feature pair. agg1h = (sum + self)*dinv.
__global__ __launch_bounds__(256) void gather1_h(
        const __half2* __restrict__ xh2, const float* __restrict__ dinv,
        const int* __restrict__ row_off, const int* __restrict__ csr_src,
        int N, __half2* __restrict__ agg1h) {
    int node = (blockIdx.x * 256 + threadIdx.x) >> 5;
    if (node >= N) return;
    int l = threadIdx.x & 31;
    int beg = row_off[node], end = row_off[node + 1];
    float2 sv = __half22float2(xh2[(long long)node * 32 + l]);  // self (pre-scaled)
    float ax = sv.x, ay = sv.y;
    int j = beg;
    for (; j + 4 <= end; j += 4) {
        int s0 = csr_src[j], s1 = csr_src[j + 1];
        int s2 = csr_src[j + 2], s3 = csr_src[j + 3];
        float2 v0 = __half22float2(xh2[(long long)s0 * 32 + l]);
        float2 v1 = __half22float2(xh2[(long long)s1 * 32 + l]);
        float2 v2 = __half22float2(xh2[(long long)s2 * 32 + l]);
        float2 v3 = __half22float2(xh2[(long long)s3 * 32 + l]);
        ax += (v0.x + v1.x) + (v2.x + v3.x);
        ay += (v0.y + v1.y) + (v2.y + v3.y);
    }
    for (; j < end; ++j) {
        int s = csr_src[j];
        float2 v = __half22float2(xh2[(long long)s * 32 + l]);
        ax += v.x; ay += v.y;
    }
    float di = dinv[node];
    agg1h[(long long)node * 32 + l] = __floats2half2_rn(ax * di, ay * di);
}

// z2h = (relu(agg1 @ W1 + b1) @ W2) * dinv   (pre-scaled fp16, 3.2MB -> L2-fit)
__global__ __launch_bounds__(256) void dense1_fused(
        const __half2* __restrict__ agg1h, const float* __restrict__ W1,
        const float* __restrict__ b1, const float* __restrict__ W2,
        const float* __restrict__ dinv, int N, __half2* __restrict__ z2h) {
    __shared__ float sW1[F_IN * H1DIM];
    __shared__ float sW2[H1DIM * H2DIM];
    __shared__ float sb1[H1DIM];
    for (int t = threadIdx.x; t < F_IN * H1DIM; t += blockDim.x) sW1[t] = W1[t];
    for (int t = threadIdx.x; t < H1DIM * H2DIM; t += blockDim.x) sW2[t] = W2[t];
    for (int t = threadIdx.x; t < H1DIM; t += blockDim.x) sb1[t] = b1[t];
    __syncthreads();

    int i = blockIdx.x * blockDim.x + threadIdx.x;
    if (i >= N) return;

    float a[F_IN];
#pragma unroll
    for (int p = 0; p < 32; p++) {
        float2 v = __half22float2(agg1h[(long long)i * 32 + p]);
        a[2 * p] = v.x; a[2 * p + 1] = v.y;
    }

    float acc[H2DIM];
#pragma unroll
    for (int c = 0; c < H2DIM; c++) acc[c] = 0.f;

    for (int k = 0; k < H1DIM; k++) {
        float h = sb1[k];
#pragma unroll
        for (int f = 0; f < F_IN; f++) h = fmaf(a[f], sW1[f * H1DIM + k], h);
        h = fmaxf(h, 0.f);
#pragma unroll
        for (int c = 0; c < H2DIM; c++) acc[c] = fmaf(h, sW2[k * H2DIM + c], acc[c]);
    }
    float di = dinv[i];
#pragma unroll
    for (int p = 0; p < 8; p++)
        z2h[(long long)i * 8 + p] = __floats2half2_rn(acc[2 * p] * di, acc[2 * p + 1] * di);
}

// One wave per node; 8 subgroups of 8 lanes stride the edge list (32B/edge
// gathers); shuffle-reduce; fused relu + final head.
__global__ __launch_bounds__(256) void gather2_final_h(
        const __half2* __restrict__ z2h, const float* __restrict__ dinv,
        const int* __restrict__ row_off, const int* __restrict__ csr_src,
        const float* __restrict__ b2, const float* __restrict__ Wl,
        const float* __restrict__ bl, int N, float* __restrict__ out) {
    int node = blockIdx.x * 4 + (threadIdx.x >> 6);
    if (node >= N) return;
    int lane = threadIdx.x & 63;
    int p = lane & 7, sub = lane >> 3;
    int beg = row_off[node], end = row_off[node + 1];
    float ax = 0.f, ay = 0.f;
    if (sub == 0) {  // self-loop (pre-scaled)
        float2 v = __half22float2(z2h[(long long)node * 8 + p]);
        ax = v.x; ay = v.y;
    }
    for (int j = beg + sub; j < end; j += 8) {
        int s = csr_src[j];
        float2 v = __half22float2(z2h[(long long)s * 8 + p]);
        ax += v.x; ay += v.y;
    }
    ax += __shfl_xor(ax, 8);  ay += __shfl_xor(ay, 8);
    ax += __shfl_xor(ax, 16); ay += __shfl_xor(ay, 16);
    ax += __shfl_xor(ax, 32); ay += __shfl_xor(ay, 32);
    float di = dinv[node];
    float2 bb = ((const float2*)b2)[p];
    float hx = fmaxf(ax * di + bb.x, 0.f);
    float hy = fmaxf(ay * di + bb.y, 0.f);

    float o = (lane < C_OUT) ? bl[lane] : 0.f;
#pragma unroll
    for (int cc = 0; cc < 8; ++cc) {
        float gx = __shfl(hx, cc);  // lane cc holds pair cc (sub==0)
        float gy = __shfl(hy, cc);
        if (lane < C_OUT) {
            o = fmaf(gx, Wl[(2 * cc) * C_OUT + lane], o);
            o = fmaf(gy, Wl[(2 * cc + 1) * C_OUT + lane], o);
        }
    }
    if (lane < C_OUT) out[(long long)node * C_OUT + lane] = o;
}

extern "C" void kernel_launch(void* const* d_in, const int* in_sizes, int n_in,
                              void* d_out, int out_size, void* d_ws, size_t ws_size,
                              hipStream_t stream) {
    const float* x  = (const float*)d_in[0];
    const int*   ei = (const int*)d_in[1];   // [2, E]: src row then dst row
    const float* W1 = (const float*)d_in[2];
    const float* b1 = (const float*)d_in[3];
    const float* W2 = (const float*)d_in[4];
    const float* b2 = (const float*)d_in[5];
    const float* Wl = (const float*)d_in[6];
    const float* bl = (const float*)d_in[7];
    float* out = (float*)d_out;

    const int N = in_sizes[0] / F_IN;
    const int E = in_sizes[1] / 2;

    size_t off = 0;
    auto carve = [&](size_t bytes) {
        void* p = (char*)d_ws + off;
        off += (bytes + 255) & ~(size_t)255;
        return p;
    };
    float*   dinv    = (float*)  carve((size_t)N * sizeof(float));
    int*     row_off = (int*)    carve(((size_t)N + 1) * sizeof(int));
    int*     csr_src = (int*)    carve((size_t)E * sizeof(int));
    __half2* xh2     = (__half2*)carve((size_t)N * 32 * sizeof(__half2));
    size_t agg_bytes = (size_t)N * 32 * sizeof(__half2);
    size_t pr_bytes  = (size_t)E * sizeof(unsigned long long);
    __half2* agg1h   = (__half2*)carve(agg_bytes > pr_bytes ? agg_bytes : pr_bytes);
    __half2* z2h     = (__half2*)carve((size_t)N * 8 * sizeof(__half2));
    int*     bcnt    = (int*)    carve(NB * sizeof(int));
    int*     boff    = (int*)    carve((NB + 1) * sizeof(int));
    int*     bcur    = (int*)    carve(NB * sizeof(int));
    // pairs aliases agg1h: pairs dead after build_csr_convert, before gather1_h
    // writes agg1h (stream-ordered).
    unsigned long long* pairs = (unsigned long long*)agg1h;

    const int nbuckets_used = (N + (1 << BSZ_LOG) - 1) >> BSZ_LOG;  // 782

    hipMemsetAsync(bcnt, 0, NB * sizeof(int), stream);
    bucket_count<<<208, 256, 0, stream>>>(ei, E, bcnt);
    bucket_scan<<<1, NB, 0, stream>>>(bcnt, boff, bcur);
    bucket_scatter<<<(E + 256 * SC_PER_TH - 1) / (256 * SC_PER_TH), 256, 0, stream>>>(
        ei, E, bcur, pairs);
    build_csr_convert<<<nbuckets_used, 256, 0, stream>>>(
        pairs, boff, x, N, dinv, row_off, csr_src, xh2);

    gather1_h<<<(N + 7) / 8, 256, 0, stream>>>(xh2, dinv, row_off, csr_src, N, agg1h);
    dense1_fused<<<(N + 255) / 256, 256, 0, stream>>>(agg1h, W1, b1, W2, dinv, N, z2h);
    gather2_final_h<<<(N + 3) / 4, 256, 0, stream>>>(z2h, dinv, row_off, csr_src,
                                                     b2, Wl, bl, N, out);
}

// Round 5
// 179.041 us; speedup vs baseline: 3.3712x; 1.3825x over previous
//
#include <hip/hip_runtime.h>
#include <hip/hip_fp16.h>

// GCN 2-layer + head. Round 5: dense layer via MFMA (fp16 in, f32 accum).
// agg[i] = (sum_{s->i} xs[s] + xs[i]) * dinv[i],  xs[s] = x[s]*dinv[s] (fp16)
// dense: z2 = (relu(agg1 @ W1 + b1) @ W2) * dinv, all in one MFMA kernel.

#define F_IN 64
#define H1DIM 128
#define H2DIM 16
#define C_OUT 10

#define NB 1024        // number of buckets (power of 2)
#define BSZ_LOG 7      // 128 nodes per bucket -> bucket = dst >> 7
#define SC_PER_TH 16   // edges per thread in bucket_scatter (4096/block)

typedef _Float16 f16x8 __attribute__((ext_vector_type(8)));
typedef _Float16 f16x4 __attribute__((ext_vector_type(4)));
typedef float f32x4 __attribute__((ext_vector_type(4)));

__global__ void bucket_count(const int* __restrict__ ei, int E,
                             int* __restrict__ bucket_cnt) {
    __shared__ int h[NB];
    for (int t = threadIdx.x; t < NB; t += blockDim.x) h[t] = 0;
    __syncthreads();
    int stride = gridDim.x * blockDim.x;
    for (int e = blockIdx.x * blockDim.x + threadIdx.x; e < E; e += stride) {
        int d = ei[E + e];
        atomicAdd(&h[d >> BSZ_LOG], 1);
    }
    __syncthreads();
    for (int t = threadIdx.x; t < NB; t += blockDim.x)
        if (h[t]) atomicAdd(&bucket_cnt[t], h[t]);
}

__global__ void bucket_scan(const int* __restrict__ bucket_cnt,
                            int* __restrict__ bucket_off,
                            int* __restrict__ bucket_cursor) {
    __shared__ int sh[NB];
    int tid = threadIdx.x;
    int v = bucket_cnt[tid];
    sh[tid] = v;
    __syncthreads();
#pragma unroll
    for (int off = 1; off < NB; off <<= 1) {
        int t = (tid >= off) ? sh[tid - off] : 0;
        __syncthreads();
        sh[tid] += t;
        __syncthreads();
    }
    int ex = sh[tid] - v;
    bucket_off[tid] = ex;
    bucket_cursor[tid] = ex;
    if (tid == NB - 1) bucket_off[NB] = sh[tid];
}

// Each block: 4096-edge chunk. LDS hist -> one global atomic per (block,bucket)
// -> rank via LDS cursor -> write packed (d<<32|s) pairs bucket-major.
__global__ __launch_bounds__(256) void bucket_scatter(
        const int* __restrict__ ei, int E,
        int* __restrict__ bucket_cursor, unsigned long long* __restrict__ pairs) {
    __shared__ int cnt[NB];
    __shared__ int base[NB];
    for (int t = threadIdx.x; t < NB; t += 256) cnt[t] = 0;
    __syncthreads();

    long long chunk = (long long)blockIdx.x * (256 * SC_PER_TH);
    int s_[SC_PER_TH], d_[SC_PER_TH];
    int m = 0;
#pragma unroll
    for (int k = 0; k < SC_PER_TH; k++) {
        long long e = chunk + k * 256 + threadIdx.x;
        if (e < E) { s_[m] = ei[e]; d_[m] = ei[E + e]; m++; }
    }
    for (int k = 0; k < m; k++) atomicAdd(&cnt[d_[k] >> BSZ_LOG], 1);
    __syncthreads();
    for (int t = threadIdx.x; t < NB; t += 256) {
        int c = cnt[t];
        base[t] = c ? atomicAdd(&bucket_cursor[t], c) : 0;
        cnt[t] = 0;
    }
    __syncthreads();
    for (int k = 0; k < m; k++) {
        int b = d_[k] >> BSZ_LOG;
        int pos = base[b] + atomicAdd(&cnt[b], 1);
        pairs[pos] = ((unsigned long long)(unsigned)d_[k] << 32) | (unsigned)s_[k];
    }
}

// One block per bucket (128 nodes): LDS hist -> dinv + row_off (scan) ->
// csr_src scatter into contiguous window -> convert x rows to fp16*dinv.
__global__ __launch_bounds__(256) void build_csr_convert(
        const unsigned long long* __restrict__ pairs,
        const int* __restrict__ bucket_off,
        const float* __restrict__ x, int N,
        float* __restrict__ dinv, int* __restrict__ row_off,
        int* __restrict__ csr_src, __half2* __restrict__ xh2) {
    int b = blockIdx.x;
    int base_node = b << BSZ_LOG;
    int nn = min(128, N - base_node);
    __shared__ int cnt[128];
    __shared__ int sc[128];
    __shared__ int cur[128];
    __shared__ float sdi[128];
    int tid = threadIdx.x;
    if (tid < 128) cnt[tid] = 0;
    __syncthreads();

    int pbeg = bucket_off[b], pend = bucket_off[b + 1];
    for (int j = pbeg + tid; j < pend; j += 256)
        atomicAdd(&cnt[(int)(pairs[j] >> 32) - base_node], 1);
    __syncthreads();

    int v = (tid < 128) ? cnt[tid] : 0;
    if (tid < 128) sc[tid] = v;
    __syncthreads();
#pragma unroll
    for (int off = 1; off < 128; off <<= 1) {
        int t = (tid < 128 && tid >= off) ? sc[tid - off] : 0;
        __syncthreads();
        if (tid < 128) sc[tid] += t;
        __syncthreads();
    }
    if (tid < nn) {
        int ro = pbeg + sc[tid] - v;
        row_off[base_node + tid] = ro;
        cur[tid] = ro;
        float di = rsqrtf((float)(v + 1));  // +1 self-loop
        dinv[base_node + tid] = di;
        sdi[tid] = di;
    }
    if (b == 0 && tid == 0) row_off[N] = bucket_off[NB];
    __syncthreads();

    for (int j = pbeg + tid; j < pend; j += 256) {
        unsigned long long p = pairs[j];
        int d = (int)(p >> 32), s = (int)(p & 0xffffffffu);
        int pos = atomicAdd(&cur[d - base_node], 1);
        csr_src[pos] = s;
    }

    // xh2[i][l] = half2(x[i][2l], x[i][2l+1]) * dinv[i]
    const float2* x2 = (const float2*)x;
    int total = nn * 32;
    for (int t = tid; t < total; t += 256) {
        int nl = t >> 5, l = t & 31;
        float di = sdi[nl];
        long long idx = (long long)(base_node + nl) * 32 + l;
        float2 xv = x2[idx];
        xh2[idx] = __floats2half2_rn(xv.x * di, xv.y * di);
    }
}

// 32-lane group per node, lane = half2 feature pair. agg1h = (sum + self)*dinv.
__global__ __launch_bounds__(256) void gather1_h(
        const __half2* __restrict__ xh2, const float* __restrict__ dinv,
        const int* __restrict__ row_off, const int* __restrict__ csr_src,
        int N, __half2* __restrict__ agg1h) {
    int node = (blockIdx.x * 256 + threadIdx.x) >> 5;
    if (node >= N) return;
    int l = threadIdx.x & 31;
    int beg = row_off[node], end = row_off[node + 1];
    float2 sv = __half22float2(xh2[(long long)node * 32 + l]);  // self (pre-scaled)
    float ax = sv.x, ay = sv.y;
    int j = beg;
    for (; j + 4 <= end; j += 4) {
        int s0 = csr_src[j], s1 = csr_src[j + 1];
        int s2 = csr_src[j + 2], s3 = csr_src[j + 3];
        float2 v0 = __half22float2(xh2[(long long)s0 * 32 + l]);
        float2 v1 = __half22float2(xh2[(long long)s1 * 32 + l]);
        float2 v2 = __half22float2(xh2[(long long)s2 * 32 + l]);
        float2 v3 = __half22float2(xh2[(long long)s3 * 32 + l]);
        ax += (v0.x + v1.x) + (v2.x + v3.x);
        ay += (v0.y + v1.y) + (v2.y + v3.y);
    }
    for (; j < end; ++j) {
        int s = csr_src[j];
        float2 v = __half22float2(xh2[(long long)s * 32 + l]);
        ax += v.x; ay += v.y;
    }
    float di = dinv[node];
    agg1h[(long long)node * 32 + l] = __floats2half2_rn(ax * di, ay * di);
}

// Pack W1 [64][128] and W2 [128][16] (f32, row-major) into fp16 MFMA B-fragment
// order for mfma_f32_16x16x32_f16: frag[lane].j = W[kbase + (lane>>4)*8 + j][col16 + (lane&15)]
__global__ __launch_bounds__(256) void pack_weights(
        const float* __restrict__ W1, const float* __restrict__ W2,
        f16x8* __restrict__ W1p, f16x8* __restrict__ W2p) {
    int s = blockIdx.x * 256 + threadIdx.x;
    if (s < 1024) {                 // 8 tiles x 2 kfrags x 64 lanes
        int frag = s >> 6, lane = s & 63;
        int tile = frag >> 1, kf = frag & 1;
        int c = lane & 15, g = lane >> 4;
        f16x8 v;
#pragma unroll
        for (int j = 0; j < 8; ++j)
            v[j] = (_Float16)W1[(kf * 32 + g * 8 + j) * H1DIM + tile * 16 + c];
        W1p[s] = v;
    } else if (s < 1024 + 256) {    // 4 kfrags x 64 lanes
        int s2 = s - 1024;
        int f = s2 >> 6, lane = s2 & 63;
        int c = lane & 15, g = lane >> 4;
        f16x8 v;
#pragma unroll
        for (int j = 0; j < 8; ++j)
            v[j] = (_Float16)W2[(f * 32 + g * 8 + j) * H2DIM + c];
        W2p[s2] = v;
    }
}

// One wave = 16 nodes. GEMM1 (K=64) as H^T = W1tile^T @ X^T (16 MFMA),
// bias+relu, per-wave XOR-swizzled LDS transpose, GEMM2 (K=128, 4 MFMA),
// scale by dinv, store fp16.
__global__ __launch_bounds__(256) void dense1_mfma(
        const _Float16* __restrict__ agg, const f16x8* __restrict__ W1p,
        const f16x8* __restrict__ W2p, const float* __restrict__ b1,
        const float* __restrict__ dinv, int N, _Float16* __restrict__ z2h) {
    __shared__ float sb1[H1DIM];
    __shared__ _Float16 Hl[4][16 * H1DIM];   // 4 KB per wave
    if (threadIdx.x < H1DIM) sb1[threadIdx.x] = b1[threadIdx.x];
    __syncthreads();
    const int wave = threadIdx.x >> 6, lane = threadIdx.x & 63;
    const int c = lane & 15, g = lane >> 4;
    const int nodeBase = blockIdx.x * 64 + wave * 16;

    int nld = nodeBase + c; if (nld > N - 1) nld = N - 1;
    const f16x8 a0 = *(const f16x8*)(agg + (size_t)nld * 64 + g * 8);        // k 0..31
    const f16x8 a1 = *(const f16x8*)(agg + (size_t)nld * 64 + 32 + g * 8);   // k 32..63

    _Float16* hl = Hl[wave];
    const f32x4 zero = {0.f, 0.f, 0.f, 0.f};
#pragma unroll
    for (int t = 0; t < 8; ++t) {
        f32x4 d = __builtin_amdgcn_mfma_f32_16x16x32_f16(W1p[(t * 2 + 1) * 64 + lane], a1, zero, 0, 0, 0);
        d = __builtin_amdgcn_mfma_f32_16x16x32_f16(W1p[(t * 2 + 0) * 64 + lane], a0, d, 0, 0, 0);
        // lane holds H[node=c][h1 = t*16 + g*4 + r]
        f16x4 hv;
#pragma unroll
        for (int r = 0; r < 4; ++r)
            hv[r] = (_Float16)fmaxf(d[r] + sb1[t * 16 + g * 4 + r], 0.f);
        unsigned byte = ((unsigned)c * 256 + (unsigned)t * 32 + (unsigned)g * 8) ^ ((unsigned)(c & 7) << 4);
        *(f16x4*)((char*)hl + byte) = hv;
    }

    f32x4 acc = zero;
#pragma unroll
    for (int f = 0; f < 4; ++f) {
        unsigned byte = ((unsigned)c * 256 + (unsigned)f * 64 + (unsigned)g * 16) ^ ((unsigned)(c & 7) << 4);
        f16x8 a2 = *(const f16x8*)((char*)hl + byte);   // H[node=c][k = f*32 + g*8 + j]
        acc = __builtin_amdgcn_mfma_f32_16x16x32_f16(a2, W2p[f * 64 + lane], acc, 0, 0, 0);
    }
    // lane holds z2[node = nodeBase + g*4 + r][col = c]
#pragma unroll
    for (int r = 0; r < 4; ++r) {
        int node = nodeBase + g * 4 + r;
        if (node < N) z2h[(size_t)node * 16 + c] = (_Float16)(acc[r] * dinv[node]);
    }
}

// One wave per node; 8 subgroups of 8 lanes stride the edge list (32B/edge
// gathers); shuffle-reduce; fused relu + final head.
__global__ __launch_bounds__(256) void gather2_final_h(
        const __half2* __restrict__ z2h, const float* __restrict__ dinv,
        const int* __restrict__ row_off, const int* __restrict__ csr_src,
        const float* __restrict__ b2, const float* __restrict__ Wl,
        const float* __restrict__ bl, int N, float* __restrict__ out) {
    int node = blockIdx.x * 4 + (threadIdx.x >> 6);
    if (node >= N) return;
    int lane = threadIdx.x & 63;
    int p = lane & 7, sub = lane >> 3;
    int beg = row_off[node], end = row_off[node + 1];
    float ax = 0.f, ay = 0.f;
    if (sub == 0) {  // self-loop (pre-scaled)
        float2 v = __half22float2(z2h[(long long)node * 8 + p]);
        ax = v.x; ay = v.y;
    }
    for (int j = beg + sub; j < end; j += 8) {
        int s = csr_src[j];
        float2 v = __half22float2(z2h[(long long)s * 8 + p]);
        ax += v.x; ay += v.y;
    }
    ax += __shfl_xor(ax, 8);  ay += __shfl_xor(ay, 8);
    ax += __shfl_xor(ax, 16); ay += __shfl_xor(ay, 16);
    ax += __shfl_xor(ax, 32); ay += __shfl_xor(ay, 32);
    float di = dinv[node];
    float2 bb = ((const float2*)b2)[p];
    float hx = fmaxf(ax * di + bb.x, 0.f);
    float hy = fmaxf(ay * di + bb.y, 0.f);

    float o = (lane < C_OUT) ? bl[lane] : 0.f;
#pragma unroll
    for (int cc = 0; cc < 8; ++cc) {
        float gx = __shfl(hx, cc);  // lane cc holds pair cc (sub==0)
        float gy = __shfl(hy, cc);
        if (lane < C_OUT) {
            o = fmaf(gx, Wl[(2 * cc) * C_OUT + lane], o);
            o = fmaf(gy, Wl[(2 * cc + 1) * C_OUT + lane], o);
        }
    }
    if (lane < C_OUT) out[(long long)node * C_OUT + lane] = o;
}

extern "C" void kernel_launch(void* const* d_in, const int* in_sizes, int n_in,
                              void* d_out, int out_size, void* d_ws, size_t ws_size,
                              hipStream_t stream) {
    const float* x  = (const float*)d_in[0];
    const int*   ei = (const int*)d_in[1];   // [2, E]: src row then dst row
    const float* W1 = (const float*)d_in[2];
    const float* b1 = (const float*)d_in[3];
    const float* W2 = (const float*)d_in[4];
    const float* b2 = (const float*)d_in[5];
    const float* Wl = (const float*)d_in[6];
    const float* bl = (const float*)d_in[7];
    float* out = (float*)d_out;

    const int N = in_sizes[0] / F_IN;
    const int E = in_sizes[1] / 2;

    size_t off = 0;
    auto carve = [&](size_t bytes) {
        void* p = (char*)d_ws + off;
        off += (bytes + 255) & ~(size_t)255;
        return p;
    };
    float*   dinv    = (float*)  carve((size_t)N * sizeof(float));
    int*     row_off = (int*)    carve(((size_t)N + 1) * sizeof(int));
    int*     csr_src = (int*)    carve((size_t)E * sizeof(int));
    __half2* xh2     = (__half2*)carve((size_t)N * 32 * sizeof(__half2));
    size_t agg_bytes = (size_t)N * 32 * sizeof(__half2);
    size_t pr_bytes  = (size_t)E * sizeof(unsigned long long);
    __half2* agg1h   = (__half2*)carve(agg_bytes > pr_bytes ? agg_bytes : pr_bytes);
    __half2* z2h     = (__half2*)carve((size_t)N * 8 * sizeof(__half2));
    int*     bcnt    = (int*)    carve(NB * sizeof(int));
    int*     boff    = (int*)    carve((NB + 1) * sizeof(int));
    int*     bcur    = (int*)    carve(NB * sizeof(int));
    f16x8*   W1p     = (f16x8*)  carve(1024 * sizeof(f16x8));
    f16x8*   W2p     = (f16x8*)  carve(256 * sizeof(f16x8));
    // pairs aliases agg1h: pairs dead after build_csr_convert, before gather1_h
    // writes agg1h (stream-ordered).
    unsigned long long* pairs = (unsigned long long*)agg1h;

    const int nbuckets_used = (N + (1 << BSZ_LOG) - 1) >> BSZ_LOG;  // 782

    hipMemsetAsync(bcnt, 0, NB * sizeof(int), stream);
    pack_weights<<<5, 256, 0, stream>>>(W1, W2, W1p, W2p);
    bucket_count<<<208, 256, 0, stream>>>(ei, E, bcnt);
    bucket_scan<<<1, NB, 0, stream>>>(bcnt, boff, bcur);
    bucket_scatter<<<(E + 256 * SC_PER_TH - 1) / (256 * SC_PER_TH), 256, 0, stream>>>(
        ei, E, bcur, pairs);
    build_csr_convert<<<nbuckets_used, 256, 0, stream>>>(
        pairs, boff, x, N, dinv, row_off, csr_src, xh2);

    gather1_h<<<(N + 7) / 8, 256, 0, stream>>>(xh2, dinv, row_off, csr_src, N, agg1h);
    dense1_mfma<<<(N + 63) / 64, 256, 0, stream>>>(
        (const _Float16*)agg1h, W1p, W2p, b1, dinv, N, (_Float16*)z2h);
    gather2_final_h<<<(N + 3) / 4, 256, 0, stream>>>(z2h, dinv, row_off, csr_src,
                                                     b2, Wl, bl, N, out);
}

// Round 6
// 131.251 us; speedup vs baseline: 4.5988x; 1.3641x over previous
//
#include <hip/hip_runtime.h>
#include <hip/hip_fp16.h>

// GCN 2-layer + head. Round 6: MLP-friendly gathers (node-per-lane-octet,
// 4-wide unrolled independent gathers, no per-edge shuffle/reduction).
// agg[i] = (sum_{s->i} xs[s] + xs[i]) * dinv[i],  xs[s] = x[s]*dinv[s] (fp16)
// dense: z2 = (relu(agg1 @ W1 + b1) @ W2) * dinv  (MFMA, fp16 in, f32 accum)

#define F_IN 64
#define H1DIM 128
#define H2DIM 16
#define C_OUT 10

#define NB 1024        // number of buckets (power of 2)
#define BSZ_LOG 7      // 128 nodes per bucket -> bucket = dst >> 7
#define SC_PER_TH 16   // edges per thread in bucket_scatter (4096/block)

typedef _Float16 f16x8 __attribute__((ext_vector_type(8)));
typedef _Float16 f16x4 __attribute__((ext_vector_type(4)));
typedef float f32x4 __attribute__((ext_vector_type(4)));

__global__ void bucket_count(const int* __restrict__ ei, int E,
                             int* __restrict__ bucket_cnt) {
    __shared__ int h[NB];
    for (int t = threadIdx.x; t < NB; t += blockDim.x) h[t] = 0;
    __syncthreads();
    int stride = gridDim.x * blockDim.x;
    for (int e = blockIdx.x * blockDim.x + threadIdx.x; e < E; e += stride) {
        int d = ei[E + e];
        atomicAdd(&h[d >> BSZ_LOG], 1);
    }
    __syncthreads();
    for (int t = threadIdx.x; t < NB; t += blockDim.x)
        if (h[t]) atomicAdd(&bucket_cnt[t], h[t]);
}

__global__ void bucket_scan(const int* __restrict__ bucket_cnt,
                            int* __restrict__ bucket_off,
                            int* __restrict__ bucket_cursor) {
    __shared__ int sh[NB];
    int tid = threadIdx.x;
    int v = bucket_cnt[tid];
    sh[tid] = v;
    __syncthreads();
#pragma unroll
    for (int off = 1; off < NB; off <<= 1) {
        int t = (tid >= off) ? sh[tid - off] : 0;
        __syncthreads();
        sh[tid] += t;
        __syncthreads();
    }
    int ex = sh[tid] - v;
    bucket_off[tid] = ex;
    bucket_cursor[tid] = ex;
    if (tid == NB - 1) bucket_off[NB] = sh[tid];
}

// Each block: 4096-edge chunk. LDS hist -> one global atomic per (block,bucket)
// -> rank via LDS cursor -> write packed (d<<32|s) pairs bucket-major.
__global__ __launch_bounds__(256) void bucket_scatter(
        const int* __restrict__ ei, int E,
        int* __restrict__ bucket_cursor, unsigned long long* __restrict__ pairs) {
    __shared__ int cnt[NB];
    __shared__ int base[NB];
    for (int t = threadIdx.x; t < NB; t += 256) cnt[t] = 0;
    __syncthreads();

    long long chunk = (long long)blockIdx.x * (256 * SC_PER_TH);
    int s_[SC_PER_TH], d_[SC_PER_TH];
    int m = 0;
#pragma unroll
    for (int k = 0; k < SC_PER_TH; k++) {
        long long e = chunk + k * 256 + threadIdx.x;
        if (e < E) { s_[m] = ei[e]; d_[m] = ei[E + e]; m++; }
    }
    for (int k = 0; k < m; k++) atomicAdd(&cnt[d_[k] >> BSZ_LOG], 1);
    __syncthreads();
    for (int t = threadIdx.x; t < NB; t += 256) {
        int c = cnt[t];
        base[t] = c ? atomicAdd(&bucket_cursor[t], c) : 0;
        cnt[t] = 0;
    }
    __syncthreads();
    for (int k = 0; k < m; k++) {
        int b = d_[k] >> BSZ_LOG;
        int pos = base[b] + atomicAdd(&cnt[b], 1);
        pairs[pos] = ((unsigned long long)(unsigned)d_[k] << 32) | (unsigned)s_[k];
    }
}

// One block per bucket (128 nodes): LDS hist -> dinv + row_off (scan) ->
// csr_src scatter into contiguous window -> convert x rows to fp16*dinv.
__global__ __launch_bounds__(256) void build_csr_convert(
        const unsigned long long* __restrict__ pairs,
        const int* __restrict__ bucket_off,
        const float* __restrict__ x, int N,
        float* __restrict__ dinv, int* __restrict__ row_off,
        int* __restrict__ csr_src, __half2* __restrict__ xh2) {
    int b = blockIdx.x;
    int base_node = b << BSZ_LOG;
    int nn = min(128, N - base_node);
    __shared__ int cnt[128];
    __shared__ int sc[128];
    __shared__ int cur[128];
    __shared__ float sdi[128];
    int tid = threadIdx.x;
    if (tid < 128) cnt[tid] = 0;
    __syncthreads();

    int pbeg = bucket_off[b], pend = bucket_off[b + 1];
    for (int j = pbeg + tid; j < pend; j += 256)
        atomicAdd(&cnt[(int)(pairs[j] >> 32) - base_node], 1);
    __syncthreads();

    int v = (tid < 128) ? cnt[tid] : 0;
    if (tid < 128) sc[tid] = v;
    __syncthreads();
#pragma unroll
    for (int off = 1; off < 128; off <<= 1) {
        int t = (tid < 128 && tid >= off) ? sc[tid - off] : 0;
        __syncthreads();
        if (tid < 128) sc[tid] += t;
        __syncthreads();
    }
    if (tid < nn) {
        int ro = pbeg + sc[tid] - v;
        row_off[base_node + tid] = ro;
        cur[tid] = ro;
        float di = rsqrtf((float)(v + 1));  // +1 self-loop
        dinv[base_node + tid] = di;
        sdi[tid] = di;
    }
    if (b == 0 && tid == 0) row_off[N] = bucket_off[NB];
    __syncthreads();

    for (int j = pbeg + tid; j < pend; j += 256) {
        unsigned long long p = pairs[j];
        int d = (int)(p >> 32), s = (int)(p & 0xffffffffu);
        int pos = atomicAdd(&cur[d - base_node], 1);
        csr_src[pos] = s;
    }

    // xh2[i][l] = half2(x[i][2l], x[i][2l+1]) * dinv[i]
    const float2* x2 = (const float2*)x;
    int total = nn * 32;
    for (int t = tid; t < total; t += 256) {
        int nl = t >> 5, l = t & 31;
        float di = sdi[nl];
        long long idx = (long long)(base_node + nl) * 32 + l;
        float2 xv = x2[idx];
        xh2[idx] = __floats2half2_rn(xv.x * di, xv.y * di);
    }
}

// 8 lanes per node (lane = f16x8 chunk of the 64-f row), 8 nodes per wave.
// Entire edge row processed by the octet with 4-wide independent gathers.
// No cross-lane reduction needed.
__global__ __launch_bounds__(256) void gather1_h2(
        const f16x8* __restrict__ xh8, const float* __restrict__ dinv,
        const int* __restrict__ row_off, const int* __restrict__ csr_src,
        int N, f16x8* __restrict__ agg1h8) {
    int node = (blockIdx.x * 256 + threadIdx.x) >> 3;
    if (node >= N) return;
    int p = threadIdx.x & 7;
    int beg = row_off[node], end = row_off[node + 1];
    f16x8 self = xh8[(size_t)node * 8 + p];
    float acc[8];
#pragma unroll
    for (int q = 0; q < 8; q++) acc[q] = (float)self[q];
    int j = beg;
    for (; j + 4 <= end; j += 4) {
        int s0 = csr_src[j], s1 = csr_src[j + 1];
        int s2 = csr_src[j + 2], s3 = csr_src[j + 3];
        f16x8 v0 = xh8[(size_t)s0 * 8 + p];
        f16x8 v1 = xh8[(size_t)s1 * 8 + p];
        f16x8 v2 = xh8[(size_t)s2 * 8 + p];
        f16x8 v3 = xh8[(size_t)s3 * 8 + p];
#pragma unroll
        for (int q = 0; q < 8; q++)
            acc[q] += ((float)v0[q] + (float)v1[q]) + ((float)v2[q] + (float)v3[q]);
    }
    for (; j < end; ++j) {
        f16x8 v = xh8[(size_t)csr_src[j] * 8 + p];
#pragma unroll
        for (int q = 0; q < 8; q++) acc[q] += (float)v[q];
    }
    float di = dinv[node];
    f16x8 o;
#pragma unroll
    for (int q = 0; q < 8; q++) o[q] = (_Float16)(acc[q] * di);
    agg1h8[(size_t)node * 8 + p] = o;
}

// Pack W1 [64][128] and W2 [128][16] (f32, row-major) into fp16 MFMA B-fragment
// order for mfma_f32_16x16x32_f16.
__global__ __launch_bounds__(256) void pack_weights(
        const float* __restrict__ W1, const float* __restrict__ W2,
        f16x8* __restrict__ W1p, f16x8* __restrict__ W2p) {
    int s = blockIdx.x * 256 + threadIdx.x;
    if (s < 1024) {                 // 8 tiles x 2 kfrags x 64 lanes
        int frag = s >> 6, lane = s & 63;
        int tile = frag >> 1, kf = frag & 1;
        int c = lane & 15, g = lane >> 4;
        f16x8 v;
#pragma unroll
        for (int j = 0; j < 8; ++j)
            v[j] = (_Float16)W1[(kf * 32 + g * 8 + j) * H1DIM + tile * 16 + c];
        W1p[s] = v;
    } else if (s < 1024 + 256) {    // 4 kfrags x 64 lanes
        int s2 = s - 1024;
        int f = s2 >> 6, lane = s2 & 63;
        int c = lane & 15, g = lane >> 4;
        f16x8 v;
#pragma unroll
        for (int j = 0; j < 8; ++j)
            v[j] = (_Float16)W2[(f * 32 + g * 8 + j) * H2DIM + c];
        W2p[s2] = v;
    }
}

// One wave = 16 nodes. GEMM1 (K=64) as H^T = W1tile^T @ X^T (16 MFMA),
// bias+relu, per-wave XOR-swizzled LDS transpose, GEMM2 (K=128, 4 MFMA),
// scale by dinv, store fp16.
__global__ __launch_bounds__(256) void dense1_mfma(
        const _Float16* __restrict__ agg, const f16x8* __restrict__ W1p,
        const f16x8* __restrict__ W2p, const float* __restrict__ b1,
        const float* __restrict__ dinv, int N, _Float16* __restrict__ z2h) {
    __shared__ float sb1[H1DIM];
    __shared__ _Float16 Hl[4][16 * H1DIM];   // 4 KB per wave
    if (threadIdx.x < H1DIM) sb1[threadIdx.x] = b1[threadIdx.x];
    __syncthreads();
    const int wave = threadIdx.x >> 6, lane = threadIdx.x & 63;
    const int c = lane & 15, g = lane >> 4;
    const int nodeBase = blockIdx.x * 64 + wave * 16;

    int nld = nodeBase + c; if (nld > N - 1) nld = N - 1;
    const f16x8 a0 = *(const f16x8*)(agg + (size_t)nld * 64 + g * 8);        // k 0..31
    const f16x8 a1 = *(const f16x8*)(agg + (size_t)nld * 64 + 32 + g * 8);   // k 32..63

    _Float16* hl = Hl[wave];
    const f32x4 zero = {0.f, 0.f, 0.f, 0.f};
#pragma unroll
    for (int t = 0; t < 8; ++t) {
        f32x4 d = __builtin_amdgcn_mfma_f32_16x16x32_f16(W1p[(t * 2 + 1) * 64 + lane], a1, zero, 0, 0, 0);
        d = __builtin_amdgcn_mfma_f32_16x16x32_f16(W1p[(t * 2 + 0) * 64 + lane], a0, d, 0, 0, 0);
        // lane holds H[node=c][h1 = t*16 + g*4 + r]
        f16x4 hv;
#pragma unroll
        for (int r = 0; r < 4; ++r)
            hv[r] = (_Float16)fmaxf(d[r] + sb1[t * 16 + g * 4 + r], 0.f);
        unsigned byte = ((unsigned)c * 256 + (unsigned)t * 32 + (unsigned)g * 8) ^ ((unsigned)(c & 7) << 4);
        *(f16x4*)((char*)hl + byte) = hv;
    }

    f32x4 acc = zero;
#pragma unroll
    for (int f = 0; f < 4; ++f) {
        unsigned byte = ((unsigned)c * 256 + (unsigned)f * 64 + (unsigned)g * 16) ^ ((unsigned)(c & 7) << 4);
        f16x8 a2 = *(const f16x8*)((char*)hl + byte);   // H[node=c][k = f*32 + g*8 + j]
        acc = __builtin_amdgcn_mfma_f32_16x16x32_f16(a2, W2p[f * 64 + lane], acc, 0, 0, 0);
    }
    // lane holds z2[node = nodeBase + g*4 + r][col = c]
#pragma unroll
    for (int r = 0; r < 4; ++r) {
        int node = nodeBase + g * 4 + r;
        if (node < N) z2h[(size_t)node * 16 + c] = (_Float16)(acc[r] * dinv[node]);
    }
}

// 8 lanes per node (lane = half2 feature pair), 32 nodes per block.
// Aggregation fully lane-local with 4-wide independent gathers; head via LDS.
__global__ __launch_bounds__(256) void gather2_final_v2(
        const __half2* __restrict__ z2h, const float* __restrict__ dinv,
        const int* __restrict__ row_off, const int* __restrict__ csr_src,
        const float* __restrict__ b2, const float* __restrict__ Wl,
        const float* __restrict__ bl, int N, float* __restrict__ out) {
    __shared__ float sWl[H2DIM * C_OUT];
    __shared__ float sb2[H2DIM];
    __shared__ float sbl[C_OUT];
    __shared__ float hbuf[32][17];
    int tid = threadIdx.x;
    if (tid < H2DIM * C_OUT) sWl[tid] = Wl[tid];
    if (tid < H2DIM) sb2[tid] = b2[tid];
    if (tid < C_OUT) sbl[tid] = bl[tid];
    __syncthreads();

    int node = blockIdx.x * 32 + (tid >> 3);
    int p = tid & 7;
    int ln = tid >> 3;
    if (node < N) {
        int beg = row_off[node], end = row_off[node + 1];
        float2 sv = __half22float2(z2h[(size_t)node * 8 + p]);  // self (pre-scaled)
        float ax = sv.x, ay = sv.y;
        int j = beg;
        for (; j + 4 <= end; j += 4) {
            int s0 = csr_src[j], s1 = csr_src[j + 1];
            int s2 = csr_src[j + 2], s3 = csr_src[j + 3];
            float2 v0 = __half22float2(z2h[(size_t)s0 * 8 + p]);
            float2 v1 = __half22float2(z2h[(size_t)s1 * 8 + p]);
            float2 v2 = __half22float2(z2h[(size_t)s2 * 8 + p]);
            float2 v3 = __half22float2(z2h[(size_t)s3 * 8 + p]);
            ax += (v0.x + v1.x) + (v2.x + v3.x);
            ay += (v0.y + v1.y) + (v2.y + v3.y);
        }
        for (; j < end; ++j) {
            float2 v = __half22float2(z2h[(size_t)csr_src[j] * 8 + p]);
            ax += v.x; ay += v.y;
        }
        float di = dinv[node];
        hbuf[ln][2 * p]     = fmaxf(ax * di + sb2[2 * p], 0.f);
        hbuf[ln][2 * p + 1] = fmaxf(ay * di + sb2[2 * p + 1], 0.f);
    }
    __syncthreads();
    if (node < N) {
        float o0 = sbl[p];
        float o1 = (p < 2) ? sbl[8 + p] : 0.f;
#pragma unroll
        for (int k = 0; k < H2DIM; k++) {
            float hk = hbuf[ln][k];
            o0 = fmaf(hk, sWl[k * C_OUT + p], o0);
            if (p < 2) o1 = fmaf(hk, sWl[k * C_OUT + 8 + p], o1);
        }
        out[(size_t)node * C_OUT + p] = o0;
        if (p < 2) out[(size_t)node * C_OUT + 8 + p] = o1;
    }
}

extern "C" void kernel_launch(void* const* d_in, const int* in_sizes, int n_in,
                              void* d_out, int out_size, void* d_ws, size_t ws_size,
                              hipStream_t stream) {
    const float* x  = (const float*)d_in[0];
    const int*   ei = (const int*)d_in[1];   // [2, E]: src row then dst row
    const float* W1 = (const float*)d_in[2];
    const float* b1 = (const float*)d_in[3];
    const float* W2 = (const float*)d_in[4];
    const float* b2 = (const float*)d_in[5];
    const float* Wl = (const float*)d_in[6];
    const float* bl = (const float*)d_in[7];
    float* out = (float*)d_out;

    const int N = in_sizes[0] / F_IN;
    const int E = in_sizes[1] / 2;

    size_t off = 0;
    auto carve = [&](size_t bytes) {
        void* p = (char*)d_ws + off;
        off += (bytes + 255) & ~(size_t)255;
        return p;
    };
    float*   dinv    = (float*)  carve((size_t)N * sizeof(float));
    int*     row_off = (int*)    carve(((size_t)N + 1) * sizeof(int));
    int*     csr_src = (int*)    carve((size_t)E * sizeof(int));
    __half2* xh2     = (__half2*)carve((size_t)N * 32 * sizeof(__half2));
    size_t agg_bytes = (size_t)N * 32 * sizeof(__half2);
    size_t pr_bytes  = (size_t)E * sizeof(unsigned long long);
    __half2* agg1h   = (__half2*)carve(agg_bytes > pr_bytes ? agg_bytes : pr_bytes);
    __half2* z2h     = (__half2*)carve((size_t)N * 8 * sizeof(__half2));
    int*     bcnt    = (int*)    carve(NB * sizeof(int));
    int*     boff    = (int*)    carve((NB + 1) * sizeof(int));
    int*     bcur    = (int*)    carve(NB * sizeof(int));
    f16x8*   W1p     = (f16x8*)  carve(1024 * sizeof(f16x8));
    f16x8*   W2p     = (f16x8*)  carve(256 * sizeof(f16x8));
    // pairs aliases agg1h: pairs dead after build_csr_convert, before gather1_h2
    // writes agg1h (stream-ordered).
    unsigned long long* pairs = (unsigned long long*)agg1h;

    const int nbuckets_used = (N + (1 << BSZ_LOG) - 1) >> BSZ_LOG;  // 782

    hipMemsetAsync(bcnt, 0, NB * sizeof(int), stream);
    pack_weights<<<5, 256, 0, stream>>>(W1, W2, W1p, W2p);
    bucket_count<<<208, 256, 0, stream>>>(ei, E, bcnt);
    bucket_scan<<<1, NB, 0, stream>>>(bcnt, boff, bcur);
    bucket_scatter<<<(E + 256 * SC_PER_TH - 1) / (256 * SC_PER_TH), 256, 0, stream>>>(
        ei, E, bcur, pairs);
    build_csr_convert<<<nbuckets_used, 256, 0, stream>>>(
        pairs, boff, x, N, dinv, row_off, csr_src, xh2);

    gather1_h2<<<((size_t)N * 8 + 255) / 256, 256, 0, stream>>>(
        (const f16x8*)xh2, dinv, row_off, csr_src, N, (f16x8*)agg1h);
    dense1_mfma<<<(N + 63) / 64, 256, 0, stream>>>(
        (const _Float16*)agg1h, W1p, W2p, b1, dinv, N, (_Float16*)z2h);
    gather2_final_v2<<<(N + 31) / 32, 256, 0, stream>>>(
        z2h, dinv, row_off, csr_src, b2, Wl, bl, N, out);
}